// Round 4
// baseline (63.963 us; speedup 1.0000x reference)
//
#include <hip/hip_runtime.h>
#include <cfloat>
#include <cmath>
#include <cstdint>

#define VV 50257
#define SPLITS 4
#define CHUNKA 12568                     // multiple of 4; last chunk = 12553
#define BMW ((CHUNKA + 31) / 32)         // 393
#define NBUCK 4096
#define CAPC 256
#define K1T 512
#define K2T 512
#define NJ 7                             // ceil((CHUNKA/4)/K1T) = ceil(3142/512)
#define NW1 (K1T / 64)

__device__ __forceinline__ unsigned fmono(float f) {
    unsigned b = __float_as_uint(f);
    return b ^ (((int)b < 0) ? 0xFFFFFFFFu : 0x80000000u);
}

// K1: per (row, chunk): penalty + max + histogram + register-cached values;
// then chunk softmax partial + chunk-local top-64 candidates to PRIVATE slots.
__global__ __launch_bounds__(K1T) void pp_k1(
    const float* __restrict__ logits, const int* __restrict__ prev,
    const float* __restrict__ rpp,
    float* __restrict__ pm, float* __restrict__ ps,
    float* __restrict__ gcv, int* __restrict__ gci, int* __restrict__ gcnt,
    float* __restrict__ out_probs, int Hp, int capc)
{
    const int sp = blockIdx.x, row = blockIdx.y;
    const int tid = threadIdx.x, lane = tid & 63, wid = tid >> 6;
    const int c0 = sp * CHUNKA;
    const int c1 = min(VV, c0 + CHUNKA);
    const int len = c1 - c0;
    const float rp = rpp[0], inv_rp = 1.0f / rp;

    __shared__ unsigned bm[BMW];
    __shared__ unsigned hist[NBUCK];
    __shared__ float red_m[NW1], red_s[NW1];
    __shared__ unsigned wtot[NW1];
    __shared__ float cand_v[CAPC];
    __shared__ int   cand_i[CAPC];
    __shared__ float sM;
    __shared__ int sT, sCnt;

    for (int i = tid; i < BMW; i += K1T) bm[i] = 0u;
    for (int i = tid; i < NBUCK; i += K1T) hist[i] = 0u;
    if (tid == 0) { sT = 0; sCnt = 0; }
    __syncthreads();

    // chunk-local prev-token bitmap (penalty idempotent w.r.t. duplicates)
    const int* prow = prev + (size_t)row * Hp;
    for (int i = tid; i < Hp; i += K1T) {
        int t = prow[i];
        if (t >= c0 && t < c1) {
            int o = t - c0;
            atomicOr(&bm[o >> 5], 1u << (o & 31));
        }
    }
    __syncthreads();

    const float* lrow = logits + (size_t)row * VV;
    float* orow = out_probs + (size_t)row * VV;
    // (row*VV + c0) mod 4 == row mod 4  (VV%4==1, CHUNKA%4==0); peel to 16B
    const int pad = (4 - (row & 3)) & 3;
    const int n4 = (len - pad) >> 2;
    const int tail0 = pad + 4 * n4;                 // chunk-local
    const float4* l4 = (const float4*)(lrow + c0 + pad);
    float4* o4 = (float4*)(orow + c0 + pad);

    // ---- pass A: load, penalize, cache in registers, hist, max ----
    float4 rv[NJ];
    float m = -FLT_MAX;
    for (int o = tid; o < pad; o += K1T) {
        float l = lrow[c0 + o];
        if ((bm[o >> 5] >> (o & 31)) & 1u) l = (l < 0.f) ? l * rp : l * inv_rp;
        atomicAdd(&hist[fmono(l) >> 20], 1u);
        m = fmaxf(m, l);
    }
    #pragma unroll
    for (int j = 0; j < NJ; ++j) {
        int k = tid + j * K1T;
        if (k < n4) {
            float4 v = l4[k];
            int ob = pad + 4 * k;
            float x;
            x = v.x; if ((bm[(ob+0) >> 5] >> ((ob+0) & 31)) & 1u) x = (x < 0.f) ? x * rp : x * inv_rp;
            atomicAdd(&hist[fmono(x) >> 20], 1u); m = fmaxf(m, x); v.x = x;
            x = v.y; if ((bm[(ob+1) >> 5] >> ((ob+1) & 31)) & 1u) x = (x < 0.f) ? x * rp : x * inv_rp;
            atomicAdd(&hist[fmono(x) >> 20], 1u); m = fmaxf(m, x); v.y = x;
            x = v.z; if ((bm[(ob+2) >> 5] >> ((ob+2) & 31)) & 1u) x = (x < 0.f) ? x * rp : x * inv_rp;
            atomicAdd(&hist[fmono(x) >> 20], 1u); m = fmaxf(m, x); v.z = x;
            x = v.w; if ((bm[(ob+3) >> 5] >> ((ob+3) & 31)) & 1u) x = (x < 0.f) ? x * rp : x * inv_rp;
            atomicAdd(&hist[fmono(x) >> 20], 1u); m = fmaxf(m, x); v.w = x;
            rv[j] = v;
        }
    }
    for (int o = tail0 + tid; o < len; o += K1T) {
        float l = lrow[c0 + o];
        if ((bm[o >> 5] >> (o & 31)) & 1u) l = (l < 0.f) ? l * rp : l * inv_rp;
        atomicAdd(&hist[fmono(l) >> 20], 1u);
        m = fmaxf(m, l);
    }

    // ---- zero output chunk (independent stores; drained at kernel end) ----
    for (int o = tid; o < pad; o += K1T) orow[c0 + o] = 0.f;
    const float4 z4 = make_float4(0.f, 0.f, 0.f, 0.f);
    for (int k = tid; k < n4; k += K1T) o4[k] = z4;
    for (int o = tail0 + tid; o < len; o += K1T) orow[c0 + o] = 0.f;

    // ---- chunk max ----
    #pragma unroll
    for (int off = 32; off; off >>= 1) m = fmaxf(m, __shfl_down(m, off));
    if (lane == 0) red_m[wid] = m;
    __syncthreads();                     // hist complete, red_m visible
    if (tid == 0) {
        float M = red_m[0];
        for (int w = 1; w < NW1; ++w) M = fmaxf(M, red_m[w]);
        sM = M;
    }

    // ---- local top-64 threshold: hierarchical suffix scan, 8 buckets/thread ----
    unsigned c = 0;
    #pragma unroll
    for (int j = 0; j < 8; ++j) c += hist[tid * 8 + j];
    unsigned v = c;
    #pragma unroll
    for (int off = 1; off < 64; off <<= 1) {
        unsigned o = __shfl_down(v, off);
        if (lane + off < 64) v += o;
    }
    if (lane == 0) wtot[wid] = v;
    __syncthreads();
    unsigned add = 0;
    for (int w = wid + 1; w < NW1; ++w) add += wtot[w];
    const unsigned mySuf = v + add;
    const unsigned sufExcl = mySuf - c;
    if (mySuf >= 64u && sufExcl < 64u) {
        unsigned above = sufExcl;
        for (int b = tid * 8 + 7; b >= tid * 8; --b) {
            above += hist[b];
            if (above >= 64u) { sT = b; break; }
        }
    }
    __syncthreads();
    const unsigned T = (unsigned)sT;
    const float M = sM;
    const int cmax = min(capc, CAPC);

    // ---- pass B (registers only): softmax partial + candidate extraction ----
    float s = 0.0f;
    for (int o = tid; o < pad; o += K1T) {
        float l = lrow[c0 + o];
        if ((bm[o >> 5] >> (o & 31)) & 1u) l = (l < 0.f) ? l * rp : l * inv_rp;
        s += __expf(l - M);
        if ((fmono(l) >> 20) >= T) {
            int p = atomicAdd(&sCnt, 1);
            if (p < cmax) { cand_v[p] = l; cand_i[p] = c0 + o; }
        }
    }
    #pragma unroll
    for (int j = 0; j < NJ; ++j) {
        int k = tid + j * K1T;
        if (k < n4) {
            float4 vv = rv[j];
            int gi = c0 + pad + 4 * k;
            s += __expf(vv.x - M);
            if ((fmono(vv.x) >> 20) >= T) { int p = atomicAdd(&sCnt, 1); if (p < cmax) { cand_v[p] = vv.x; cand_i[p] = gi + 0; } }
            s += __expf(vv.y - M);
            if ((fmono(vv.y) >> 20) >= T) { int p = atomicAdd(&sCnt, 1); if (p < cmax) { cand_v[p] = vv.y; cand_i[p] = gi + 1; } }
            s += __expf(vv.z - M);
            if ((fmono(vv.z) >> 20) >= T) { int p = atomicAdd(&sCnt, 1); if (p < cmax) { cand_v[p] = vv.z; cand_i[p] = gi + 2; } }
            s += __expf(vv.w - M);
            if ((fmono(vv.w) >> 20) >= T) { int p = atomicAdd(&sCnt, 1); if (p < cmax) { cand_v[p] = vv.w; cand_i[p] = gi + 3; } }
        }
    }
    for (int o = tail0 + tid; o < len; o += K1T) {
        float l = lrow[c0 + o];
        if ((bm[o >> 5] >> (o & 31)) & 1u) l = (l < 0.f) ? l * rp : l * inv_rp;
        s += __expf(l - M);
        if ((fmono(l) >> 20) >= T) {
            int p = atomicAdd(&sCnt, 1);
            if (p < cmax) { cand_v[p] = l; cand_i[p] = c0 + o; }
        }
    }
    #pragma unroll
    for (int off = 32; off; off >>= 1) s += __shfl_down(s, off);
    if (lane == 0) red_s[wid] = s;
    __syncthreads();                     // sCnt + cand + red_s final

    const int slot = row * SPLITS + sp;
    if (tid == 0) {
        float Ss = red_s[0];
        for (int w = 1; w < NW1; ++w) Ss += red_s[w];
        pm[slot] = M;
        ps[slot] = Ss;
        gcnt[slot] = min(sCnt, cmax);
    }
    const int cnt = min(sCnt, cmax);
    for (int t = tid; t < cnt; t += K1T) {
        gcv[(size_t)slot * capc + t] = cand_v[t];
        gci[(size_t)slot * capc + t] = cand_i[t];
    }
}

// K2: per row: merge (m,s), rank-select global top-64, finale.
__global__ __launch_bounds__(K2T) void pp_k2(
    const float* __restrict__ u, const float* __restrict__ toppp,
    const float* __restrict__ tempp, const int* __restrict__ topkp,
    const float* __restrict__ pm, const float* __restrict__ ps,
    const float* __restrict__ gcv, const int* __restrict__ gci,
    const int* __restrict__ gcnt,
    float* __restrict__ out_idx, float* __restrict__ out_probs, int capc)
{
    const int row = blockIdx.x, tid = threadIdx.x;
    __shared__ float cv[SPLITS * CAPC];
    __shared__ int   cidx[SPLITS * CAPC];
    __shared__ float tv[64];
    __shared__ int   ti[64];
    __shared__ float sM, sS;

    int c4[SPLITS], off[SPLITS];
    int tot = 0;
    #pragma unroll
    for (int j = 0; j < SPLITS; ++j) {
        c4[j] = gcnt[row * SPLITS + j];
        off[j] = tot;
        tot += c4[j];
    }
    #pragma unroll
    for (int j = 0; j < SPLITS; ++j)
        for (int i = tid; i < c4[j]; i += K2T) {
            cv[off[j] + i]   = gcv[(size_t)(row * SPLITS + j) * capc + i];
            cidx[off[j] + i] = gci[(size_t)(row * SPLITS + j) * capc + i];
        }
    if (tid < 64) { tv[tid] = -FLT_MAX; ti[tid] = 0x7FFFFFFF; }
    if (tid == 0) {
        float M = pm[row * SPLITS], S = ps[row * SPLITS];
        for (int j = 1; j < SPLITS; ++j) {
            float m2 = pm[row * SPLITS + j], s2 = ps[row * SPLITS + j];
            float nm = fmaxf(M, m2);
            S = S * __expf(M - nm) + s2 * __expf(m2 - nm);
            M = nm;
        }
        sM = M; sS = S;
    }
    __syncthreads();

    // rank-select top-64 (stable by index; broadcast LDS reads)
    for (int t = tid; t < tot; t += K2T) {
        float vi = cv[t]; int ii = cidx[t];
        int r = 0;
        for (int j2 = 0; j2 < tot; ++j2) {
            float vj = cv[j2]; int ij = cidx[j2];
            r += (int)((vj > vi) || (vj == vi && ij < ii));
        }
        if (r < 64) { tv[r] = vi; ti[r] = ii; }
    }
    __syncthreads();

    // finale: top-p cutoff, temperature softmax, scatter, gumbel argmax
    if (tid < 64) {
        const int lane = tid;
        const float top_p = toppp[0];
        const float temp = tempp[0];
        int K = topkp[0]; K = min(max(K, 1), 64);
        const float M = sM, Ssum = sS;
        float vl = tv[lane];
        int ci = ti[lane];
        bool val = (vl > -FLT_MAX);
        bool act = (lane < K) && val;
        float e = act ? expf(vl - M) / Ssum : 0.0f;
        float cum = e;
        #pragma unroll
        for (int off2 = 1; off2 < 64; off2 <<= 1) {
            float pv = __shfl_up(cum, off2);
            if (lane >= off2) cum += pv;
        }
        unsigned long long bal = __ballot(act && (cum <= top_p));
        int n = (int)__popcll(bal);
        if (n < 1) n = 1;   // rank-0 always kept
        const float v0 = tv[0];
        const float invT = 1.0f / fmaxf(temp, 1e-5f);
        bool keep = (lane < n) && val;
        float w = keep ? expf((vl - v0) * invT) : 0.0f;
        float Z = w;
        #pragma unroll
        for (int off2 = 32; off2; off2 >>= 1) Z += __shfl_xor(Z, off2);
        float p = keep ? (w / Z) : 0.0f;
        if (keep) out_probs[(size_t)row * VV + ci] = p;
        float ratio = -1.0f;
        if (keep) ratio = p / (-logf(u[(size_t)row * VV + ci]));
        int bi = keep ? ci : 0x7FFFFFFF;
        #pragma unroll
        for (int off2 = 32; off2; off2 >>= 1) {
            float orat = __shfl_xor(ratio, off2);
            int oidx = __shfl_xor(bi, off2);
            if (orat > ratio || (orat == ratio && oidx < bi)) { ratio = orat; bi = oidx; }
        }
        if (lane == 0) out_idx[row] = (float)bi;
    }
}

extern "C" void kernel_launch(void* const* d_in, const int* in_sizes, int n_in,
                              void* d_out, int out_size, void* d_ws, size_t ws_size,
                              hipStream_t stream) {
    const float* logits = (const float*)d_in[0];
    const int*   prev   = (const int*)d_in[1];
    const float* u      = (const float*)d_in[2];
    const float* topp   = (const float*)d_in[3];
    const float* rp     = (const float*)d_in[4];
    const float* temp   = (const float*)d_in[5];
    const int*   topk   = (const int*)d_in[6];

    const int B  = in_sizes[0] / VV;
    const int Hp = in_sizes[1] / B;

    // workspace layout (no shared-address atomics, no memsets needed)
    char* ws = (char*)d_ws;
    int*   gcnt = (int*)ws;                             // B*SPLITS ints
    float* pm   = (float*)(ws + 8192);                  // B*SPLITS floats
    float* ps   = pm + (size_t)B * SPLITS;              // B*SPLITS floats
    char*  cbase = ws + 16384;
    long long avail = (long long)ws_size - 16384;
    int capc = (int)(avail / (8LL * B * SPLITS));
    if (capc > CAPC) capc = CAPC;
    if (capc < 64) capc = 64;                           // ws assumed large enough
    float* gcv = (float*)cbase;
    int*   gci = (int*)(cbase + (size_t)B * SPLITS * capc * 4);

    float* out = (float*)d_out;
    pp_k1<<<dim3(SPLITS, B), K1T, 0, stream>>>(
        logits, prev, rp, pm, ps, gcv, gci, gcnt, out + B, Hp, capc);
    pp_k2<<<B, K2T, 0, stream>>>(
        u, topp, temp, topk, pm, ps, gcv, gci, gcnt, out, out + B, capc);
}

// Round 5
// 32.465 us; speedup vs baseline: 1.9702x; 1.9702x over previous
//
#include <hip/hip_runtime.h>
#include <cfloat>
#include <cmath>
#include <cstdint>

#define VV 50257
#define SPLITS 4
#define CHUNKA 12568                     // multiple of 4; last chunk = 12553
#define BMW ((CHUNKA + 31) / 32)         // 393
#define NBUCK 4096
#define CAPC 256
#define K1T 512
#define K2T 512
#define NJ 7                             // ceil((CHUNKA/4)/K1T)
#define NW1 (K1T / 64)

__device__ __forceinline__ unsigned fmono(float f) {
    unsigned b = __float_as_uint(f);
    return b ^ (((int)b < 0) ? 0xFFFFFFFFu : 0x80000000u);
}
__device__ __forceinline__ float unmono(unsigned m) {
    unsigned b = (m & 0x80000000u) ? (m ^ 0x80000000u) : ~m;
    return __uint_as_float(b);
}
// sortable key: value-desc, tie -> smaller index first
__device__ __forceinline__ uint64_t mkkey(unsigned mono, int idx) {
    return ((uint64_t)mono << 32) | (unsigned)(~idx);
}

// K1: per (row, chunk): penalty + max + histogram (reg-cached values);
// chunk softmax partial + chunk-local top-64 candidate keys to PRIVATE slots.
__global__ __launch_bounds__(K1T) void pp_k1(
    const float* __restrict__ logits, const int* __restrict__ prev,
    const float* __restrict__ rpp,
    float* __restrict__ pm, float* __restrict__ ps,
    uint64_t* __restrict__ gkey, int* __restrict__ gcnt,
    float* __restrict__ out_probs, int Hp, int capc)
{
    const int sp = blockIdx.x, row = blockIdx.y;
    const int tid = threadIdx.x, lane = tid & 63, wid = tid >> 6;
    const int c0 = sp * CHUNKA;
    const int c1 = min(VV, c0 + CHUNKA);
    const int len = c1 - c0;
    const float rp = rpp[0], inv_rp = 1.0f / rp;

    __shared__ unsigned bm[BMW];
    __shared__ unsigned hist[NBUCK];
    __shared__ float red_m[NW1], red_s[NW1];
    __shared__ unsigned wtot[NW1];
    __shared__ uint64_t cand_k[CAPC];
    __shared__ float sM;
    __shared__ int sT, sCnt;

    for (int i = tid; i < BMW; i += K1T) bm[i] = 0u;
    for (int i = tid; i < NBUCK; i += K1T) hist[i] = 0u;
    if (tid == 0) { sT = 0; sCnt = 0; }
    __syncthreads();

    // chunk-local prev-token bitmap (penalty idempotent w.r.t. duplicates)
    const int* prow = prev + (size_t)row * Hp;
    for (int i = tid; i < Hp; i += K1T) {
        int t = prow[i];
        if (t >= c0 && t < c1) {
            int o = t - c0;
            atomicOr(&bm[o >> 5], 1u << (o & 31));
        }
    }
    __syncthreads();

    const float* lrow = logits + (size_t)row * VV;
    float* orow = out_probs + (size_t)row * VV;
    // (row*VV + c0) mod 4 == row mod 4  (VV%4==1, CHUNKA%4==0); peel to 16B
    const int pad = (4 - (row & 3)) & 3;
    const int n4 = (len - pad) >> 2;
    const int tail0 = pad + 4 * n4;                 // chunk-local
    const float4* l4 = (const float4*)(lrow + c0 + pad);
    float4* o4 = (float4*)(orow + c0 + pad);

    // ---- pass A: load, penalize, cache in registers, hist, max ----
    float4 rv[NJ];
    float m = -FLT_MAX;
    for (int o = tid; o < pad; o += K1T) {
        float l = lrow[c0 + o];
        if ((bm[o >> 5] >> (o & 31)) & 1u) l = (l < 0.f) ? l * rp : l * inv_rp;
        atomicAdd(&hist[fmono(l) >> 20], 1u);
        m = fmaxf(m, l);
    }
    #pragma unroll
    for (int j = 0; j < NJ; ++j) {
        int k = tid + j * K1T;
        if (k < n4) {
            float4 v = l4[k];
            int ob = pad + 4 * k;
            float x;
            x = v.x; if ((bm[(ob+0) >> 5] >> ((ob+0) & 31)) & 1u) x = (x < 0.f) ? x * rp : x * inv_rp;
            atomicAdd(&hist[fmono(x) >> 20], 1u); m = fmaxf(m, x); v.x = x;
            x = v.y; if ((bm[(ob+1) >> 5] >> ((ob+1) & 31)) & 1u) x = (x < 0.f) ? x * rp : x * inv_rp;
            atomicAdd(&hist[fmono(x) >> 20], 1u); m = fmaxf(m, x); v.y = x;
            x = v.z; if ((bm[(ob+2) >> 5] >> ((ob+2) & 31)) & 1u) x = (x < 0.f) ? x * rp : x * inv_rp;
            atomicAdd(&hist[fmono(x) >> 20], 1u); m = fmaxf(m, x); v.z = x;
            x = v.w; if ((bm[(ob+3) >> 5] >> ((ob+3) & 31)) & 1u) x = (x < 0.f) ? x * rp : x * inv_rp;
            atomicAdd(&hist[fmono(x) >> 20], 1u); m = fmaxf(m, x); v.w = x;
            rv[j] = v;
        }
    }
    for (int o = tail0 + tid; o < len; o += K1T) {
        float l = lrow[c0 + o];
        if ((bm[o >> 5] >> (o & 31)) & 1u) l = (l < 0.f) ? l * rp : l * inv_rp;
        atomicAdd(&hist[fmono(l) >> 20], 1u);
        m = fmaxf(m, l);
    }

    // ---- zero output chunk (independent stores; drained at kernel end) ----
    for (int o = tid; o < pad; o += K1T) orow[c0 + o] = 0.f;
    const float4 z4 = make_float4(0.f, 0.f, 0.f, 0.f);
    for (int k = tid; k < n4; k += K1T) o4[k] = z4;
    for (int o = tail0 + tid; o < len; o += K1T) orow[c0 + o] = 0.f;

    // ---- chunk max ----
    #pragma unroll
    for (int off = 32; off; off >>= 1) m = fmaxf(m, __shfl_down(m, off));
    if (lane == 0) red_m[wid] = m;
    __syncthreads();                     // hist complete, red_m visible
    if (tid == 0) {
        float M = red_m[0];
        for (int w = 1; w < NW1; ++w) M = fmaxf(M, red_m[w]);
        sM = M;
    }

    // ---- local top-64 threshold: hierarchical suffix scan, 8 buckets/thread ----
    unsigned c = 0;
    #pragma unroll
    for (int j = 0; j < 8; ++j) c += hist[tid * 8 + j];
    unsigned v = c;
    #pragma unroll
    for (int off = 1; off < 64; off <<= 1) {
        unsigned o = __shfl_down(v, off);
        if (lane + off < 64) v += o;
    }
    if (lane == 0) wtot[wid] = v;
    __syncthreads();
    unsigned add = 0;
    for (int w = wid + 1; w < NW1; ++w) add += wtot[w];
    const unsigned mySuf = v + add;
    const unsigned sufExcl = mySuf - c;
    if (mySuf >= 64u && sufExcl < 64u) {
        unsigned above = sufExcl;
        for (int b = tid * 8 + 7; b >= tid * 8; --b) {
            above += hist[b];
            if (above >= 64u) { sT = b; break; }
        }
    }
    __syncthreads();
    const unsigned T = (unsigned)sT;
    const float M = sM;
    const int cmax = min(capc, CAPC);

    // ---- pass B (registers only): softmax partial + packed candidate keys ----
    float s = 0.0f;
    for (int o = tid; o < pad; o += K1T) {
        float l = lrow[c0 + o];
        if ((bm[o >> 5] >> (o & 31)) & 1u) l = (l < 0.f) ? l * rp : l * inv_rp;
        s += __expf(l - M);
        unsigned mo = fmono(l);
        if ((mo >> 20) >= T) {
            int p = atomicAdd(&sCnt, 1);
            if (p < cmax) cand_k[p] = mkkey(mo, c0 + o);
        }
    }
    #pragma unroll
    for (int j = 0; j < NJ; ++j) {
        int k = tid + j * K1T;
        if (k < n4) {
            float4 vv = rv[j];
            int gi = c0 + pad + 4 * k;
            unsigned mo;
            s += __expf(vv.x - M);
            mo = fmono(vv.x);
            if ((mo >> 20) >= T) { int p = atomicAdd(&sCnt, 1); if (p < cmax) cand_k[p] = mkkey(mo, gi + 0); }
            s += __expf(vv.y - M);
            mo = fmono(vv.y);
            if ((mo >> 20) >= T) { int p = atomicAdd(&sCnt, 1); if (p < cmax) cand_k[p] = mkkey(mo, gi + 1); }
            s += __expf(vv.z - M);
            mo = fmono(vv.z);
            if ((mo >> 20) >= T) { int p = atomicAdd(&sCnt, 1); if (p < cmax) cand_k[p] = mkkey(mo, gi + 2); }
            s += __expf(vv.w - M);
            mo = fmono(vv.w);
            if ((mo >> 20) >= T) { int p = atomicAdd(&sCnt, 1); if (p < cmax) cand_k[p] = mkkey(mo, gi + 3); }
        }
    }
    for (int o = tail0 + tid; o < len; o += K1T) {
        float l = lrow[c0 + o];
        if ((bm[o >> 5] >> (o & 31)) & 1u) l = (l < 0.f) ? l * rp : l * inv_rp;
        s += __expf(l - M);
        unsigned mo = fmono(l);
        if ((mo >> 20) >= T) {
            int p = atomicAdd(&sCnt, 1);
            if (p < cmax) cand_k[p] = mkkey(mo, c0 + o);
        }
    }
    #pragma unroll
    for (int off = 32; off; off >>= 1) s += __shfl_down(s, off);
    if (lane == 0) red_s[wid] = s;
    __syncthreads();                     // sCnt + cand + red_s final

    const int slot = row * SPLITS + sp;
    if (tid == 0) {
        float Ss = red_s[0];
        for (int w = 1; w < NW1; ++w) Ss += red_s[w];
        pm[slot] = M;
        ps[slot] = Ss;
        gcnt[slot] = min(sCnt, cmax);
    }
    const int cnt = min(sCnt, cmax);
    for (int t = tid; t < cnt; t += K1T)
        gkey[(size_t)slot * capc + t] = cand_k[t];
}

// K2: per row: merge (m,s), rank-select global top-64 over packed keys, finale.
__global__ __launch_bounds__(K2T) void pp_k2(
    const float* __restrict__ u, const float* __restrict__ toppp,
    const float* __restrict__ tempp, const int* __restrict__ topkp,
    const float* __restrict__ pm, const float* __restrict__ ps,
    const uint64_t* __restrict__ gkey, const int* __restrict__ gcnt,
    float* __restrict__ out_idx, float* __restrict__ out_probs, int capc)
{
    const int row = blockIdx.x, tid = threadIdx.x;
    __shared__ uint64_t ck[SPLITS * CAPC];
    __shared__ uint64_t tk[64];
    __shared__ float sM, sS;

    int c4[SPLITS], off[SPLITS];
    int tot = 0;
    #pragma unroll
    for (int j = 0; j < SPLITS; ++j) {
        c4[j] = gcnt[row * SPLITS + j];
        off[j] = tot;
        tot += c4[j];
    }
    #pragma unroll
    for (int j = 0; j < SPLITS; ++j)
        for (int i = tid; i < c4[j]; i += K2T)
            ck[off[j] + i] = gkey[(size_t)(row * SPLITS + j) * capc + i];
    if (tid < 64) tk[tid] = 0ull;
    if (tid == 0) {
        float M = pm[row * SPLITS], S = ps[row * SPLITS];
        for (int j = 1; j < SPLITS; ++j) {
            float m2 = pm[row * SPLITS + j], s2 = ps[row * SPLITS + j];
            float nm = fmaxf(M, m2);
            S = S * __expf(M - nm) + s2 * __expf(m2 - nm);
            M = nm;
        }
        sM = M; sS = S;
    }
    __syncthreads();

    // rank-select top-64: 8-way unrolled independent LDS b64 reads
    for (int t = tid; t < tot; t += K2T) {
        const uint64_t ki = ck[t];
        int r = 0;
        int j = 0;
        for (; j + 8 <= tot; j += 8) {
            uint64_t a0 = ck[j], a1 = ck[j+1], a2 = ck[j+2], a3 = ck[j+3];
            uint64_t a4 = ck[j+4], a5 = ck[j+5], a6 = ck[j+6], a7 = ck[j+7];
            r += (int)(a0 > ki) + (int)(a1 > ki) + (int)(a2 > ki) + (int)(a3 > ki)
               + (int)(a4 > ki) + (int)(a5 > ki) + (int)(a6 > ki) + (int)(a7 > ki);
        }
        for (; j < tot; ++j) r += (int)(ck[j] > ki);
        if (r < 64) tk[r] = ki;
    }
    __syncthreads();

    // finale: top-p cutoff, temperature softmax, scatter, gumbel argmax
    if (tid < 64) {
        const int lane = tid;
        const float top_p = toppp[0];
        const float temp = tempp[0];
        int K = topkp[0]; K = min(max(K, 1), 64);
        const float M = sM, Ssum = sS;
        uint64_t k64 = tk[lane];
        bool val = (lane < min(tot, 64));
        float vl = unmono((unsigned)(k64 >> 32));
        int ci = (int)(~(unsigned)(k64 & 0xFFFFFFFFu));
        bool act = (lane < K) && val;
        float e = act ? expf(vl - M) / Ssum : 0.0f;
        float cum = e;
        #pragma unroll
        for (int off2 = 1; off2 < 64; off2 <<= 1) {
            float pv = __shfl_up(cum, off2);
            if (lane >= off2) cum += pv;
        }
        unsigned long long bal = __ballot(act && (cum <= top_p));
        int n = (int)__popcll(bal);
        if (n < 1) n = 1;   // rank-0 always kept
        const float v0 = __shfl(vl, 0);
        const float invT = 1.0f / fmaxf(temp, 1e-5f);
        bool keep = (lane < n) && val;
        float w = keep ? expf((vl - v0) * invT) : 0.0f;
        float Z = w;
        #pragma unroll
        for (int off2 = 32; off2; off2 >>= 1) Z += __shfl_xor(Z, off2);
        float p = keep ? (w / Z) : 0.0f;
        if (keep) out_probs[(size_t)row * VV + ci] = p;
        float ratio = -1.0f;
        if (keep) ratio = p / (-logf(u[(size_t)row * VV + ci]));
        int bi = keep ? ci : 0x7FFFFFFF;
        #pragma unroll
        for (int off2 = 32; off2; off2 >>= 1) {
            float orat = __shfl_xor(ratio, off2);
            int oidx = __shfl_xor(bi, off2);
            if (orat > ratio || (orat == ratio && oidx < bi)) { ratio = orat; bi = oidx; }
        }
        if (lane == 0) out_idx[row] = (float)bi;
    }
}

extern "C" void kernel_launch(void* const* d_in, const int* in_sizes, int n_in,
                              void* d_out, int out_size, void* d_ws, size_t ws_size,
                              hipStream_t stream) {
    const float* logits = (const float*)d_in[0];
    const int*   prev   = (const int*)d_in[1];
    const float* u      = (const float*)d_in[2];
    const float* topp   = (const float*)d_in[3];
    const float* rp     = (const float*)d_in[4];
    const float* temp   = (const float*)d_in[5];
    const int*   topk   = (const int*)d_in[6];

    const int B  = in_sizes[0] / VV;
    const int Hp = in_sizes[1] / B;

    // workspace layout (no shared-address atomics, no memsets needed)
    char* ws = (char*)d_ws;
    int*   gcnt = (int*)ws;                             // B*SPLITS ints
    float* pm   = (float*)(ws + 8192);                  // B*SPLITS floats
    float* ps   = pm + (size_t)B * SPLITS;              // B*SPLITS floats
    long long avail = (long long)ws_size - 16384;
    int capc = (int)(avail / (8LL * B * SPLITS));       // 8 bytes per packed key
    if (capc > CAPC) capc = CAPC;
    if (capc < 64) capc = 64;                           // ws assumed large enough
    uint64_t* gkey = (uint64_t*)(ws + 16384);

    float* out = (float*)d_out;
    pp_k1<<<dim3(SPLITS, B), K1T, 0, stream>>>(
        logits, prev, rp, pm, ps, gkey, gcnt, out + B, Hp, capc);
    pp_k2<<<B, K2T, 0, stream>>>(
        u, topp, temp, topk, pm, ps, gkey, gcnt, out, out + B, capc);
}

// Round 6
// 29.390 us; speedup vs baseline: 2.1763x; 1.1046x over previous
//
#include <hip/hip_runtime.h>
#include <cfloat>
#include <cmath>
#include <cstdint>

#define VV 50257
#define SPLITS 4
#define CHUNKA 12568                     // multiple of 4; last chunk = 12553
#define BMW ((CHUNKA + 31) / 32)         // 393
#define NBUCK 4096
#define CAPC 512
#define K1T 512
#define K2T 256                          // = SPLITS*64 keys, one thread each
#define NW1 (K1T / 64)

__device__ __forceinline__ unsigned fmono(float f) {
    unsigned b = __float_as_uint(f);
    return b ^ (((int)b < 0) ? 0xFFFFFFFFu : 0x80000000u);
}
__device__ __forceinline__ float unmono(unsigned m) {
    unsigned b = (m & 0x80000000u) ? (m ^ 0x80000000u) : ~m;
    return __uint_as_float(b);
}
// sortable key: value-desc, tie -> smaller index first
__device__ __forceinline__ uint64_t mkkey(unsigned mono, int idx) {
    return ((uint64_t)mono << 32) | (unsigned)(~idx);
}

// K1: per (row, chunk): penalty + max + histogram; chunk softmax partial;
// in-chunk SORTED top-64 keys to private slots; zero output chunk at end.
__global__ __launch_bounds__(K1T, 4) void pp_k1(
    const float* __restrict__ logits, const int* __restrict__ prev,
    const float* __restrict__ rpp,
    float* __restrict__ pm, float* __restrict__ ps,
    uint64_t* __restrict__ gkey, float* __restrict__ out_probs, int Hp)
{
    const int sp = blockIdx.x, row = blockIdx.y;
    const int tid = threadIdx.x, lane = tid & 63, wid = tid >> 6;
    const int c0 = sp * CHUNKA;
    const int c1 = min(VV, c0 + CHUNKA);
    const int len = c1 - c0;
    const float rp = rpp[0], inv_rp = 1.0f / rp;

    __shared__ unsigned bm[BMW];
    __shared__ unsigned hist[NBUCK];
    __shared__ float red_m[NW1], red_s[NW1];
    __shared__ unsigned wtot[NW1];
    __shared__ uint64_t cand_k[CAPC];
    __shared__ uint64_t top64[64];
    __shared__ float sM;
    __shared__ int sT, sCnt;

    for (int i = tid; i < BMW; i += K1T) bm[i] = 0u;
    for (int i = tid; i < NBUCK; i += K1T) hist[i] = 0u;
    if (tid == 0) { sT = 0; sCnt = 0; }
    __syncthreads();

    // chunk-local prev-token bitmap (penalty idempotent w.r.t. duplicates)
    const int* prow = prev + (size_t)row * Hp;
    const int h4 = Hp >> 2;
    const int4* prow4 = (const int4*)prow;
    for (int i = tid; i < h4; i += K1T) {
        int4 t4 = prow4[i];
        int t;
        t = t4.x; if (t >= c0 && t < c1) { int o = t - c0; atomicOr(&bm[o >> 5], 1u << (o & 31)); }
        t = t4.y; if (t >= c0 && t < c1) { int o = t - c0; atomicOr(&bm[o >> 5], 1u << (o & 31)); }
        t = t4.z; if (t >= c0 && t < c1) { int o = t - c0; atomicOr(&bm[o >> 5], 1u << (o & 31)); }
        t = t4.w; if (t >= c0 && t < c1) { int o = t - c0; atomicOr(&bm[o >> 5], 1u << (o & 31)); }
    }
    for (int i = 4 * h4 + tid; i < Hp; i += K1T) {
        int t = prow[i];
        if (t >= c0 && t < c1) { int o = t - c0; atomicOr(&bm[o >> 5], 1u << (o & 31)); }
    }
    __syncthreads();

    const float* lrow = logits + (size_t)row * VV;
    float* orow = out_probs + (size_t)row * VV;
    // (row*VV + c0) mod 4 == row mod 4  (VV%4==1, CHUNKA%4==0); peel to 16B
    const int pad = (4 - (row & 3)) & 3;
    const int n4 = (len - pad) >> 2;
    const int tail0 = pad + 4 * n4;                 // chunk-local
    const float4* l4 = (const float4*)(lrow + c0 + pad);
    float4* o4 = (float4*)(orow + c0 + pad);

    // ---- pass A: load, penalize, hist, max (no register caching) ----
    float m = -FLT_MAX;
    for (int o = tid; o < pad; o += K1T) {
        float l = lrow[c0 + o];
        if ((bm[o >> 5] >> (o & 31)) & 1u) l = (l < 0.f) ? l * rp : l * inv_rp;
        atomicAdd(&hist[fmono(l) >> 20], 1u);
        m = fmaxf(m, l);
    }
    #pragma unroll 4
    for (int k = tid; k < n4; k += K1T) {
        float4 v = l4[k];
        const int ob = pad + 4 * k;
        float x;
        x = v.x; if ((bm[(ob+0) >> 5] >> ((ob+0) & 31)) & 1u) x = (x < 0.f) ? x * rp : x * inv_rp;
        atomicAdd(&hist[fmono(x) >> 20], 1u); m = fmaxf(m, x);
        x = v.y; if ((bm[(ob+1) >> 5] >> ((ob+1) & 31)) & 1u) x = (x < 0.f) ? x * rp : x * inv_rp;
        atomicAdd(&hist[fmono(x) >> 20], 1u); m = fmaxf(m, x);
        x = v.z; if ((bm[(ob+2) >> 5] >> ((ob+2) & 31)) & 1u) x = (x < 0.f) ? x * rp : x * inv_rp;
        atomicAdd(&hist[fmono(x) >> 20], 1u); m = fmaxf(m, x);
        x = v.w; if ((bm[(ob+3) >> 5] >> ((ob+3) & 31)) & 1u) x = (x < 0.f) ? x * rp : x * inv_rp;
        atomicAdd(&hist[fmono(x) >> 20], 1u); m = fmaxf(m, x);
    }
    for (int o = tail0 + tid; o < len; o += K1T) {
        float l = lrow[c0 + o];
        if ((bm[o >> 5] >> (o & 31)) & 1u) l = (l < 0.f) ? l * rp : l * inv_rp;
        atomicAdd(&hist[fmono(l) >> 20], 1u);
        m = fmaxf(m, l);
    }

    // ---- chunk max ----
    #pragma unroll
    for (int off = 32; off; off >>= 1) m = fmaxf(m, __shfl_down(m, off));
    if (lane == 0) red_m[wid] = m;
    __syncthreads();                     // hist complete, red_m visible
    if (tid == 0) {
        float M = red_m[0];
        for (int w = 1; w < NW1; ++w) M = fmaxf(M, red_m[w]);
        sM = M;
    }

    // ---- local top-64 threshold: hierarchical suffix scan, 8 buckets/thread ----
    unsigned c = 0;
    #pragma unroll
    for (int j = 0; j < 8; ++j) c += hist[tid * 8 + j];
    unsigned v = c;
    #pragma unroll
    for (int off = 1; off < 64; off <<= 1) {
        unsigned o = __shfl_down(v, off);
        if (lane + off < 64) v += o;
    }
    if (lane == 0) wtot[wid] = v;
    __syncthreads();
    unsigned add = 0;
    for (int w = wid + 1; w < NW1; ++w) add += wtot[w];
    const unsigned mySuf = v + add;
    const unsigned sufExcl = mySuf - c;
    if (mySuf >= 64u && sufExcl < 64u) {
        unsigned above = sufExcl;
        for (int b = tid * 8 + 7; b >= tid * 8; --b) {
            above += hist[b];
            if (above >= 64u) { sT = b; break; }
        }
    }
    __syncthreads();
    const unsigned T = (unsigned)sT;
    const float M = sM;

    // ---- pass B (L2-hot re-read): softmax partial + candidate keys ----
    float s = 0.0f;
    for (int o = tid; o < pad; o += K1T) {
        float l = lrow[c0 + o];
        if ((bm[o >> 5] >> (o & 31)) & 1u) l = (l < 0.f) ? l * rp : l * inv_rp;
        s += __expf(l - M);
        unsigned mo = fmono(l);
        if ((mo >> 20) >= T) {
            int p = atomicAdd(&sCnt, 1);
            if (p < CAPC) cand_k[p] = mkkey(mo, c0 + o);
        }
    }
    #pragma unroll 4
    for (int k = tid; k < n4; k += K1T) {
        float4 vv = l4[k];
        const int gi = c0 + pad + 4 * k;
        const int ob = pad + 4 * k;
        float x; unsigned mo;
        x = vv.x; if ((bm[(ob+0) >> 5] >> ((ob+0) & 31)) & 1u) x = (x < 0.f) ? x * rp : x * inv_rp;
        s += __expf(x - M); mo = fmono(x);
        if ((mo >> 20) >= T) { int p = atomicAdd(&sCnt, 1); if (p < CAPC) cand_k[p] = mkkey(mo, gi + 0); }
        x = vv.y; if ((bm[(ob+1) >> 5] >> ((ob+1) & 31)) & 1u) x = (x < 0.f) ? x * rp : x * inv_rp;
        s += __expf(x - M); mo = fmono(x);
        if ((mo >> 20) >= T) { int p = atomicAdd(&sCnt, 1); if (p < CAPC) cand_k[p] = mkkey(mo, gi + 1); }
        x = vv.z; if ((bm[(ob+2) >> 5] >> ((ob+2) & 31)) & 1u) x = (x < 0.f) ? x * rp : x * inv_rp;
        s += __expf(x - M); mo = fmono(x);
        if ((mo >> 20) >= T) { int p = atomicAdd(&sCnt, 1); if (p < CAPC) cand_k[p] = mkkey(mo, gi + 2); }
        x = vv.w; if ((bm[(ob+3) >> 5] >> ((ob+3) & 31)) & 1u) x = (x < 0.f) ? x * rp : x * inv_rp;
        s += __expf(x - M); mo = fmono(x);
        if ((mo >> 20) >= T) { int p = atomicAdd(&sCnt, 1); if (p < CAPC) cand_k[p] = mkkey(mo, gi + 3); }
    }
    for (int o = tail0 + tid; o < len; o += K1T) {
        float l = lrow[c0 + o];
        if ((bm[o >> 5] >> (o & 31)) & 1u) l = (l < 0.f) ? l * rp : l * inv_rp;
        s += __expf(l - M);
        unsigned mo = fmono(l);
        if ((mo >> 20) >= T) {
            int p = atomicAdd(&sCnt, 1);
            if (p < CAPC) cand_k[p] = mkkey(mo, c0 + o);
        }
    }
    #pragma unroll
    for (int off = 32; off; off >>= 1) s += __shfl_down(s, off);
    if (lane == 0) red_s[wid] = s;
    __syncthreads();                     // sCnt + cand_k + red_s final

    const int slot = row * SPLITS + sp;
    if (tid == 0) {
        float Ss = red_s[0];
        for (int w = 1; w < NW1; ++w) Ss += red_s[w];
        pm[slot] = M;
        ps[slot] = Ss;
    }

    // ---- in-chunk rank-select -> SORTED top-64 (cnt >= 64 guaranteed) ----
    const int cnt = min(sCnt, CAPC);
    for (int t = tid; t < cnt; t += K1T) {
        const uint64_t ki = cand_k[t];
        int r = 0;
        int j = 0;
        for (; j + 8 <= cnt; j += 8) {
            uint64_t a0 = cand_k[j],   a1 = cand_k[j+1], a2 = cand_k[j+2], a3 = cand_k[j+3];
            uint64_t a4 = cand_k[j+4], a5 = cand_k[j+5], a6 = cand_k[j+6], a7 = cand_k[j+7];
            r += (int)(a0 > ki) + (int)(a1 > ki) + (int)(a2 > ki) + (int)(a3 > ki)
               + (int)(a4 > ki) + (int)(a5 > ki) + (int)(a6 > ki) + (int)(a7 > ki);
        }
        for (; j < cnt; ++j) r += (int)(cand_k[j] > ki);
        if (r < 64) top64[r] = ki;
    }
    __syncthreads();
    if (tid < 64) gkey[(size_t)slot * 64 + tid] = top64[tid];

    // ---- zero output chunk LAST (no barrier waits on these stores) ----
    for (int o = tid; o < pad; o += K1T) orow[c0 + o] = 0.f;
    const float4 z4 = make_float4(0.f, 0.f, 0.f, 0.f);
    for (int k = tid; k < n4; k += K1T) o4[k] = z4;
    for (int o = tail0 + tid; o < len; o += K1T) orow[c0 + o] = 0.f;
}

// K2: per row: merge (m,s); rank 4 sorted 64-lists via binary search; finale.
__global__ __launch_bounds__(K2T) void pp_k2(
    const float* __restrict__ u, const float* __restrict__ toppp,
    const float* __restrict__ tempp, const int* __restrict__ topkp,
    const float* __restrict__ pm, const float* __restrict__ ps,
    const uint64_t* __restrict__ gkey,
    float* __restrict__ out_idx, float* __restrict__ out_probs)
{
    const int row = blockIdx.x, tid = threadIdx.x;
    __shared__ uint64_t ck[SPLITS * 64];
    __shared__ uint64_t tk[64];
    __shared__ float sM, sS;

    ck[tid] = gkey[(size_t)row * (SPLITS * 64) + tid];
    if (tid == 0) {
        float M = pm[row * SPLITS], S = ps[row * SPLITS];
        for (int j = 1; j < SPLITS; ++j) {
            float m2 = pm[row * SPLITS + j], s2 = ps[row * SPLITS + j];
            float nm = fmaxf(M, m2);
            S = S * __expf(M - nm) + s2 * __expf(m2 - nm);
            M = nm;
        }
        sM = M; sS = S;
    }
    __syncthreads();

    // global rank = own position + #greater in each other sorted (desc) list
    {
        const int j = tid >> 6;          // own list
        const uint64_t ki = ck[tid];
        int r = tid & 63;                // rank within own list
        #pragma unroll
        for (int o = 0; o < SPLITS; ++o) {
            if (o == j) continue;
            const uint64_t* ls = &ck[o * 64];
            int lo = 0, hi = 64;
            while (lo < hi) {            // first idx with ls[idx] < ki (keys unique)
                int mid = (lo + hi) >> 1;
                if (ls[mid] > ki) lo = mid + 1; else hi = mid;
            }
            r += lo;
        }
        if (r < 64) tk[r] = ki;
    }
    __syncthreads();

    // finale: top-p cutoff, temperature softmax, scatter, gumbel argmax
    if (tid < 64) {
        const int lane = tid;
        const float top_p = toppp[0];
        const float temp = tempp[0];
        int K = topkp[0]; K = min(max(K, 1), 64);
        const float M = sM, Ssum = sS;
        const uint64_t k64 = tk[lane];
        const float vl = unmono((unsigned)(k64 >> 32));
        const int ci = (int)(~(unsigned)(k64 & 0xFFFFFFFFu));
        bool act = (lane < K);
        float e = act ? expf(vl - M) / Ssum : 0.0f;
        float cum = e;
        #pragma unroll
        for (int off2 = 1; off2 < 64; off2 <<= 1) {
            float pv = __shfl_up(cum, off2);
            if (lane >= off2) cum += pv;
        }
        unsigned long long bal = __ballot(act && (cum <= top_p));
        int n = (int)__popcll(bal);
        if (n < 1) n = 1;   // rank-0 always kept
        const float v0 = __shfl(vl, 0);
        const float invT = 1.0f / fmaxf(temp, 1e-5f);
        bool keep = (lane < n);
        float w = keep ? expf((vl - v0) * invT) : 0.0f;
        float Z = w;
        #pragma unroll
        for (int off2 = 32; off2; off2 >>= 1) Z += __shfl_xor(Z, off2);
        float p = keep ? (w / Z) : 0.0f;
        if (keep) out_probs[(size_t)row * VV + ci] = p;
        float ratio = -1.0f;
        if (keep) ratio = p / (-logf(u[(size_t)row * VV + ci]));
        int bi = keep ? ci : 0x7FFFFFFF;
        #pragma unroll
        for (int off2 = 32; off2; off2 >>= 1) {
            float orat = __shfl_xor(ratio, off2);
            int oidx = __shfl_xor(bi, off2);
            if (orat > ratio || (orat == ratio && oidx < bi)) { ratio = orat; bi = oidx; }
        }
        if (lane == 0) out_idx[row] = (float)bi;
    }
}

extern "C" void kernel_launch(void* const* d_in, const int* in_sizes, int n_in,
                              void* d_out, int out_size, void* d_ws, size_t ws_size,
                              hipStream_t stream) {
    const float* logits = (const float*)d_in[0];
    const int*   prev   = (const int*)d_in[1];
    const float* u      = (const float*)d_in[2];
    const float* topp   = (const float*)d_in[3];
    const float* rp     = (const float*)d_in[4];
    const float* temp   = (const float*)d_in[5];
    const int*   topk   = (const int*)d_in[6];

    const int B  = in_sizes[0] / VV;
    const int Hp = in_sizes[1] / B;

    // workspace layout (private slots only; no memsets, no global atomics)
    char* ws = (char*)d_ws;
    float* pm = (float*)ws;                             // B*SPLITS floats
    float* ps = pm + (size_t)B * SPLITS;                // B*SPLITS floats
    uint64_t* gkey = (uint64_t*)(ws + 16384);           // B*SPLITS*64 keys

    float* out = (float*)d_out;
    pp_k1<<<dim3(SPLITS, B), K1T, 0, stream>>>(
        logits, prev, rp, pm, ps, gkey, out + B, Hp);
    pp_k2<<<B, K2T, 0, stream>>>(
        u, topp, temp, topk, pm, ps, gkey, out, out + B);
}